// Round 3
// baseline (2188.773 us; speedup 1.0000x reference)
//
#include <hip/hip_runtime.h>

#define NEG_SLOPE 0.01f

// ---------------- CSR build ----------------

__global__ __launch_bounds__(256) void zero_int_kernel(int* __restrict__ p, int n) {
  int i = blockIdx.x * 256 + threadIdx.x;
  if (i < n) p[i] = 0;
}

__global__ __launch_bounds__(256) void hist_kernel(const int* __restrict__ dst, int* __restrict__ cnt, int E) {
  int i = blockIdx.x * 256 + threadIdx.x;
  if (i < E) atomicAdd(&cnt[dst[i]], 1);
}

// Block scans 2048 elements (256 threads x 8). Writes per-element exclusive
// scan (within block) to rp, block total to bsum.
__global__ __launch_bounds__(256) void scan1_kernel(const int* __restrict__ cnt, int* __restrict__ rp,
                                                    int* __restrict__ bsum, int n) {
  __shared__ int sh[256];
  int t = threadIdx.x;
  int base = blockIdx.x * 2048 + t * 8;
  int v[8];
  int tot = 0;
#pragma unroll
  for (int j = 0; j < 8; ++j) {
    int i = base + j;
    int c = (i < n) ? cnt[i] : 0;
    v[j] = tot;
    tot += c;
  }
  sh[t] = tot;
  __syncthreads();
  for (int off = 1; off < 256; off <<= 1) {
    int x = sh[t];
    int y = (t >= off) ? sh[t - off] : 0;
    __syncthreads();
    sh[t] = x + y;
    __syncthreads();
  }
  int pre = sh[t] - tot;  // exclusive prefix of this thread within block
#pragma unroll
  for (int j = 0; j < 8; ++j) {
    int i = base + j;
    if (i < n) rp[i] = pre + v[j];
  }
  if (t == 255) bsum[blockIdx.x] = sh[255];
}

__global__ void scan2_kernel(int* __restrict__ bsum, int nb, int* __restrict__ rp, int n) {
  if (threadIdx.x == 0 && blockIdx.x == 0) {
    int run = 0;
    for (int i = 0; i < nb; ++i) {
      int t = bsum[i];
      bsum[i] = run;
      run += t;
    }
    rp[n] = run;  // total edge count
  }
}

__global__ __launch_bounds__(256) void scan3_kernel(int* __restrict__ rp, const int* __restrict__ bsum,
                                                    int* __restrict__ cursor, int n) {
  int i = blockIdx.x * 256 + threadIdx.x;
  if (i < n) {
    int v = rp[i] + bsum[i >> 11];  // 2048 = 1<<11 per scan1 block
    rp[i] = v;
    cursor[i] = v;
  }
}

__global__ __launch_bounds__(256) void scatter_kernel(const int* __restrict__ src, const int* __restrict__ dst,
                                                      const float* __restrict__ vals, int* __restrict__ cursor,
                                                      int* __restrict__ csrc, float* __restrict__ cval, int E) {
  int i = blockIdx.x * 256 + threadIdx.x;
  if (i < E) {
    int d = dst[i];
    int pos = atomicAdd(&cursor[d], 1);
    csrc[pos] = src[i];
    cval[pos] = vals[i];
  }
}

// ---------------- GEMM (f32 vector ALU, 128x64 tile, BK=16) ----------------

__global__ __launch_bounds__(256) void gemm_f32_kernel(const float* __restrict__ A, const float* __restrict__ B,
                                                       float* __restrict__ C, int M, int N, int K) {
  __shared__ __align__(16) float As[16][132];  // [k][m], padded: 2-way conflict max on staging writes
  __shared__ __align__(16) float Bs[16][64];   // [k][n]
  int t = threadIdx.x;
  int tn = t & 15, tm = t >> 4;
  int row0 = blockIdx.x * 128, col0 = blockIdx.y * 64;
  float acc[8][4] = {};
  for (int k0 = 0; k0 < K; k0 += 16) {
    // A tile 128x16: 512 float4s, 2 rounds of 256 threads
#pragma unroll
    for (int r = 0; r < 2; ++r) {
      int idx = t + r * 256;
      int arow = idx >> 2, ac4 = idx & 3;
      int grow = row0 + arow;
      float4 v = make_float4(0.f, 0.f, 0.f, 0.f);
      if (grow < M) v = *(const float4*)&A[(size_t)grow * K + k0 + ac4 * 4];
      As[ac4 * 4 + 0][arow] = v.x;
      As[ac4 * 4 + 1][arow] = v.y;
      As[ac4 * 4 + 2][arow] = v.z;
      As[ac4 * 4 + 3][arow] = v.w;
    }
    // B tile 16x64
    {
      int brow = t >> 4, bc4 = t & 15;
      int gcol = col0 + bc4 * 4;
      float4 v;
      if (gcol + 3 < N) {
        v = *(const float4*)&B[(size_t)(k0 + brow) * N + gcol];
      } else {
        float tmp[4];
#pragma unroll
        for (int j = 0; j < 4; ++j) tmp[j] = (gcol + j < N) ? B[(size_t)(k0 + brow) * N + gcol + j] : 0.f;
        v = make_float4(tmp[0], tmp[1], tmp[2], tmp[3]);
      }
      *(float4*)&Bs[brow][bc4 * 4] = v;
    }
    __syncthreads();
#pragma unroll
    for (int k = 0; k < 16; ++k) {
      float4 a0 = *(const float4*)&As[k][tm * 8];
      float4 a1 = *(const float4*)&As[k][tm * 8 + 4];
      float4 b0 = *(const float4*)&Bs[k][tn * 4];
      float a[8] = {a0.x, a0.y, a0.z, a0.w, a1.x, a1.y, a1.z, a1.w};
      float b[4] = {b0.x, b0.y, b0.z, b0.w};
#pragma unroll
      for (int i = 0; i < 8; ++i)
#pragma unroll
        for (int j = 0; j < 4; ++j) acc[i][j] = fmaf(a[i], b[j], acc[i][j]);
    }
    __syncthreads();
  }
#pragma unroll
  for (int i = 0; i < 8; ++i) {
    int grow = row0 + tm * 8 + i;
    if (grow >= M) continue;
#pragma unroll
    for (int j = 0; j < 4; ++j) {
      int gcol = col0 + tn * 4 + j;
      if (gcol < N) C[(size_t)grow * N + gcol] = acc[i][j];
    }
  }
}

// ---------------- SPMM (CSR gather, one wave per node) ----------------

// D == 256: each lane holds float4 of the output row.
__global__ __launch_bounds__(256) void spmm_d256_kernel(const float* __restrict__ x, const int* __restrict__ rp,
                                                        const int* __restrict__ csrc, const float* __restrict__ cval,
                                                        const float* __restrict__ bias, float* __restrict__ out,
                                                        int n) {
  int node = blockIdx.x * 4 + (threadIdx.x >> 6);
  int lane = threadIdx.x & 63;
  if (node >= n) return;
  int s = rp[node], e = rp[node + 1];
  float4 acc = make_float4(0.f, 0.f, 0.f, 0.f);
  int p = s;
  for (; p + 4 <= e; p += 4) {
    int s0 = csrc[p], s1 = csrc[p + 1], s2 = csrc[p + 2], s3 = csrc[p + 3];
    float v0 = cval[p], v1 = cval[p + 1], v2 = cval[p + 2], v3 = cval[p + 3];
    float4 x0 = *(const float4*)&x[(size_t)s0 * 256 + lane * 4];
    float4 x1 = *(const float4*)&x[(size_t)s1 * 256 + lane * 4];
    float4 x2 = *(const float4*)&x[(size_t)s2 * 256 + lane * 4];
    float4 x3 = *(const float4*)&x[(size_t)s3 * 256 + lane * 4];
    acc.x = fmaf(v0, x0.x, acc.x); acc.y = fmaf(v0, x0.y, acc.y);
    acc.z = fmaf(v0, x0.z, acc.z); acc.w = fmaf(v0, x0.w, acc.w);
    acc.x = fmaf(v1, x1.x, acc.x); acc.y = fmaf(v1, x1.y, acc.y);
    acc.z = fmaf(v1, x1.z, acc.z); acc.w = fmaf(v1, x1.w, acc.w);
    acc.x = fmaf(v2, x2.x, acc.x); acc.y = fmaf(v2, x2.y, acc.y);
    acc.z = fmaf(v2, x2.z, acc.z); acc.w = fmaf(v2, x2.w, acc.w);
    acc.x = fmaf(v3, x3.x, acc.x); acc.y = fmaf(v3, x3.y, acc.y);
    acc.z = fmaf(v3, x3.z, acc.z); acc.w = fmaf(v3, x3.w, acc.w);
  }
  for (; p < e; ++p) {
    int s0 = csrc[p];
    float v0 = cval[p];
    float4 x0 = *(const float4*)&x[(size_t)s0 * 256 + lane * 4];
    acc.x = fmaf(v0, x0.x, acc.x); acc.y = fmaf(v0, x0.y, acc.y);
    acc.z = fmaf(v0, x0.z, acc.z); acc.w = fmaf(v0, x0.w, acc.w);
  }
  float4 b = *(const float4*)&bias[lane * 4];
  acc.x += b.x; acc.y += b.y; acc.z += b.z; acc.w += b.w;
  acc.x = acc.x > 0.f ? acc.x : acc.x * NEG_SLOPE;
  acc.y = acc.y > 0.f ? acc.y : acc.y * NEG_SLOPE;
  acc.z = acc.z > 0.f ? acc.z : acc.z * NEG_SLOPE;
  acc.w = acc.w > 0.f ? acc.w : acc.w * NEG_SLOPE;
  *(float4*)&out[(size_t)node * 256 + lane * 4] = acc;
}

// Small D (40): lanes 0..D-1 each own one output element.
__global__ __launch_bounds__(256) void spmm_small_kernel(const float* __restrict__ x, const int* __restrict__ rp,
                                                         const int* __restrict__ csrc, const float* __restrict__ cval,
                                                         const float* __restrict__ bias, float* __restrict__ out,
                                                         int n, int D) {
  int node = blockIdx.x * 4 + (threadIdx.x >> 6);
  int lane = threadIdx.x & 63;
  if (node >= n) return;
  int l = lane < D ? lane : 0;  // clamp to stay in-bounds; lanes >= D discarded
  int s = rp[node], e = rp[node + 1];
  float acc = 0.f;
  int p = s;
  for (; p + 4 <= e; p += 4) {
    int s0 = csrc[p], s1 = csrc[p + 1], s2 = csrc[p + 2], s3 = csrc[p + 3];
    float v0 = cval[p], v1 = cval[p + 1], v2 = cval[p + 2], v3 = cval[p + 3];
    acc = fmaf(v0, x[(size_t)s0 * D + l], acc);
    acc = fmaf(v1, x[(size_t)s1 * D + l], acc);
    acc = fmaf(v2, x[(size_t)s2 * D + l], acc);
    acc = fmaf(v3, x[(size_t)s3 * D + l], acc);
  }
  for (; p < e; ++p) acc = fmaf(cval[p], x[(size_t)csrc[p] * D + l], acc);
  if (lane < D) {
    float r = acc + bias[lane];
    out[(size_t)node * D + lane] = r > 0.f ? r : r * NEG_SLOPE;
  }
}

// ---------------- launch ----------------

extern "C" void kernel_launch(void* const* d_in, const int* in_sizes, int n_in,
                              void* d_out, int out_size, void* d_ws, size_t ws_size,
                              hipStream_t stream) {
  const float* features = (const float*)d_in[0];
  const int* esrc = (const int*)d_in[1];
  const int* edst = (const int*)d_in[2];
  const float* evals = (const float*)d_in[3];
  const float* W1 = (const float*)d_in[4];
  const float* b1 = (const float*)d_in[5];
  const float* Wh = (const float*)d_in[6];
  const float* bh = (const float*)d_in[7];
  const float* W2 = (const float*)d_in[8];
  const float* b2 = (const float*)d_in[9];

  const int E = in_sizes[1];
  const int hid = in_sizes[5];          // 256
  const int ncls = in_sizes[9];         // 40
  const int nfeat = in_sizes[4] / hid;  // 512
  const int Nn = in_sizes[0] / nfeat;   // 100000

  char* ws = (char*)d_ws;
  size_t off = 0;
  auto alloc = [&](size_t bytes) {
    char* p = ws + off;
    off += (bytes + 255) & ~(size_t)255;
    return p;
  };
  float* h1 = (float*)alloc((size_t)Nn * hid * 4);
  float* h2 = (float*)alloc((size_t)Nn * hid * 4);
  int* rp = (int*)alloc((size_t)(Nn + 1) * 4);
  int* cursor = (int*)alloc((size_t)Nn * 4);  // doubles as counts buffer
  int nb = (Nn + 2047) / 2048;
  int* bsum = (int*)alloc((size_t)nb * 4);
  int* csrc = (int*)alloc((size_t)E * 4);
  float* cval = (float*)alloc((size_t)E * 4);
  float* g3 = h1;  // layer-3 GEMM output reuses h1 (free by then)
  (void)ws_size;

  dim3 blk(256);

  // --- build CSR (dst-sorted) on device; amortized over 3 spmms ---
  zero_int_kernel<<<(Nn + 255) / 256, blk, 0, stream>>>(cursor, Nn);
  hist_kernel<<<(E + 255) / 256, blk, 0, stream>>>(edst, cursor, E);
  scan1_kernel<<<nb, blk, 0, stream>>>(cursor, rp, bsum, Nn);
  scan2_kernel<<<1, 64, 0, stream>>>(bsum, nb, rp, Nn);
  scan3_kernel<<<(Nn + 255) / 256, blk, 0, stream>>>(rp, bsum, cursor, Nn);
  scatter_kernel<<<(E + 255) / 256, blk, 0, stream>>>(esrc, edst, evals, cursor, csrc, cval, E);

  // --- layer 1: [N,512]x[512,256] -> spmm -> +b1, leaky ---
  gemm_f32_kernel<<<dim3((Nn + 127) / 128, (hid + 63) / 64), blk, 0, stream>>>(features, W1, h1, Nn, hid, nfeat);
  spmm_d256_kernel<<<(Nn + 3) / 4, blk, 0, stream>>>(h1, rp, csrc, cval, b1, h2, Nn);

  // --- layer 2: [N,256]x[256,256] ---
  gemm_f32_kernel<<<dim3((Nn + 127) / 128, (hid + 63) / 64), blk, 0, stream>>>(h2, Wh, h1, Nn, hid, hid);
  spmm_d256_kernel<<<(Nn + 3) / 4, blk, 0, stream>>>(h1, rp, csrc, cval, bh, h2, Nn);

  // --- layer 3: [N,256]x[256,40] ---
  gemm_f32_kernel<<<dim3((Nn + 127) / 128, (ncls + 63) / 64), blk, 0, stream>>>(h2, W2, g3, Nn, ncls, hid);
  spmm_small_kernel<<<(Nn + 3) / 4, blk, 0, stream>>>(g3, rp, csrc, cval, b2, (float*)d_out, Nn, ncls);
}

// Round 8
// 1378.280 us; speedup vs baseline: 1.5880x; 1.5880x over previous
//
#include <hip/hip_runtime.h>

#define NEG_SLOPE 0.01f

typedef __attribute__((ext_vector_type(8))) short bf16x8;
typedef __attribute__((ext_vector_type(4))) float f32x4;

static __device__ __forceinline__ unsigned short f2bf(float f) {
  unsigned int u = __float_as_uint(f);
  return (unsigned short)((u + 0x7fffu + ((u >> 16) & 1u)) >> 16);  // RNE
}
static __device__ __forceinline__ float bf2f(unsigned short s) {
  return __uint_as_float(((unsigned int)s) << 16);
}
static __device__ __forceinline__ float leaky(float r) { return r > 0.f ? r : r * NEG_SLOPE; }

// ---------------- CSR build (verified in baseline) ----------------

__global__ __launch_bounds__(256) void zero_int_kernel(int* __restrict__ p, int n) {
  int i = blockIdx.x * 256 + threadIdx.x;
  if (i < n) p[i] = 0;
}

__global__ __launch_bounds__(256) void hist_kernel(const int* __restrict__ dst, int* __restrict__ cnt, int E) {
  int i = blockIdx.x * 256 + threadIdx.x;
  if (i < E) atomicAdd(&cnt[dst[i]], 1);
}

__global__ __launch_bounds__(256) void scan1_kernel(const int* __restrict__ cnt, int* __restrict__ rp,
                                                    int* __restrict__ bsum, int n) {
  __shared__ int sh[256];
  int t = threadIdx.x;
  int base = blockIdx.x * 2048 + t * 8;
  int v[8];
  int tot = 0;
#pragma unroll
  for (int j = 0; j < 8; ++j) {
    int i = base + j;
    int c = (i < n) ? cnt[i] : 0;
    v[j] = tot;
    tot += c;
  }
  sh[t] = tot;
  __syncthreads();
  for (int off = 1; off < 256; off <<= 1) {
    int x = sh[t];
    int y = (t >= off) ? sh[t - off] : 0;
    __syncthreads();
    sh[t] = x + y;
    __syncthreads();
  }
  int pre = sh[t] - tot;
#pragma unroll
  for (int j = 0; j < 8; ++j) {
    int i = base + j;
    if (i < n) rp[i] = pre + v[j];
  }
  if (t == 255) bsum[blockIdx.x] = sh[255];
}

__global__ void scan2_kernel(int* __restrict__ bsum, int nb, int* __restrict__ rp, int n) {
  if (threadIdx.x == 0 && blockIdx.x == 0) {
    int run = 0;
    for (int i = 0; i < nb; ++i) {
      int t = bsum[i];
      bsum[i] = run;
      run += t;
    }
    rp[n] = run;
  }
}

__global__ __launch_bounds__(256) void scan3_kernel(int* __restrict__ rp, const int* __restrict__ bsum,
                                                    int* __restrict__ cursor, int n) {
  int i = blockIdx.x * 256 + threadIdx.x;
  if (i < n) {
    int v = rp[i] + bsum[i >> 11];
    rp[i] = v;
    cursor[i] = v;
  }
}

__global__ __launch_bounds__(256) void scatter_kernel(const int* __restrict__ src, const int* __restrict__ dst,
                                                      const float* __restrict__ vals, int* __restrict__ cursor,
                                                      int* __restrict__ csrc, float* __restrict__ cval, int E) {
  int i = blockIdx.x * 256 + threadIdx.x;
  if (i < E) {
    int d = dst[i];
    int pos = atomicAdd(&cursor[d], 1);
    csrc[pos] = src[i];
    cval[pos] = vals[i];
  }
}

// ---------------- weight transpose + cvt: Wt[n][k] = bf16(W[k][n]), rows n>=Nreal zero ----------------

__global__ __launch_bounds__(256) void cvt_w_kernel(const float* __restrict__ W, unsigned short* __restrict__ Wt,
                                                    int K, int Nreal, int Npad) {
  int i = blockIdx.x * 256 + threadIdx.x;
  if (i >= Npad * K) return;
  int n = i / K, k = i - n * K;
  float v = (n < Nreal) ? W[(size_t)k * Nreal + n] : 0.f;
  Wt[i] = f2bf(v);
}

// ---------------- bf16 MFMA GEMM ----------------
// C[bf16, MxN] = A[f32, MxK] @ W, with W given transposed as Wt[N][K] bf16.
// N multiple of 64, K multiple of 64. Tile 128x64, BK=64, 4 waves (2x2), 16x16x32 MFMA.
// Fragment layout per learn_hip m92 (ref-checked): A lane l&15 = row, (l>>4)*8 = k-chunk;
// B from [N][K]: lane l&15 = col(n), same k-chunk; C/D col=lane&15, row=(lane>>4)*4+reg (m89/m91).

__global__ __launch_bounds__(256) void gemm_mfma_kernel(const float* __restrict__ A, const unsigned short* __restrict__ Wt,
                                                        unsigned short* __restrict__ C, int M, int N, int K) {
  __shared__ __align__(16) short As[128 * 72];  // [row][k], +8 pad: <=2-way bank conflicts
  __shared__ __align__(16) short Bs[64 * 72];   // [n][k]
  const int t = threadIdx.x;
  const int lane = t & 63;
  const int w = t >> 6;
  const int wr = w >> 1;  // 0..1: 64-row block
  const int wc = w & 1;   // 0..1: 32-col block
  const int row0 = blockIdx.x * 128;
  const int col0 = blockIdx.y * 64;
  const int l15 = lane & 15;
  const int l16 = lane >> 4;  // 0..3

  f32x4 acc[4][2];
#pragma unroll
  for (int m = 0; m < 4; ++m)
#pragma unroll
    for (int n = 0; n < 2; ++n) acc[m][n] = (f32x4){0.f, 0.f, 0.f, 0.f};

  for (int k0 = 0; k0 < K; k0 += 64) {
    __syncthreads();  // previous tile's LDS reads done
    // stage A 128x64: f32 -> bf16. 2048 float4 chunks = 8 iters x 256 threads.
#pragma unroll
    for (int it = 0; it < 8; ++it) {
      int idx = it * 256 + t;
      int row = idx >> 4;   // 16 chunks of 4 per 64-el row
      int c4 = idx & 15;
      int grow = row0 + row;
      float4 v = make_float4(0.f, 0.f, 0.f, 0.f);
      if (grow < M) v = *(const float4*)&A[(size_t)grow * K + k0 + c4 * 4];
      unsigned int lo = (unsigned int)f2bf(v.x) | ((unsigned int)f2bf(v.y) << 16);
      unsigned int hi = (unsigned int)f2bf(v.z) | ((unsigned int)f2bf(v.w) << 16);
      *(uint2*)&As[row * 72 + c4 * 4] = make_uint2(lo, hi);
    }
    // stage B 64x64 bf16: 512 16B chunks = 2 iters x 256 threads.
#pragma unroll
    for (int it = 0; it < 2; ++it) {
      int idx = it * 256 + t;
      int n = idx >> 3;
      int c8 = idx & 7;
      uint4 v = *(const uint4*)&Wt[(size_t)(col0 + n) * K + k0 + c8 * 8];
      *(uint4*)&Bs[n * 72 + c8 * 8] = v;
    }
    __syncthreads();
#pragma unroll
    for (int kk = 0; kk < 64; kk += 32) {
      bf16x8 a[4], b[2];
#pragma unroll
      for (int m = 0; m < 4; ++m)
        a[m] = *(const bf16x8*)&As[(wr * 64 + m * 16 + l15) * 72 + kk + l16 * 8];
#pragma unroll
      for (int n = 0; n < 2; ++n)
        b[n] = *(const bf16x8*)&Bs[(wc * 32 + n * 16 + l15) * 72 + kk + l16 * 8];
#pragma unroll
      for (int m = 0; m < 4; ++m)
#pragma unroll
        for (int n = 0; n < 2; ++n)
          acc[m][n] = __builtin_amdgcn_mfma_f32_16x16x32_bf16(a[m], b[n], acc[m][n], 0, 0, 0);
    }
  }
  // epilogue: C[row][col] bf16
#pragma unroll
  for (int m = 0; m < 4; ++m) {
#pragma unroll
    for (int j = 0; j < 4; ++j) {
      int grow = row0 + wr * 64 + m * 16 + l16 * 4 + j;
      if (grow < M) {
#pragma unroll
        for (int n = 0; n < 2; ++n) {
          int gcol = col0 + wc * 32 + n * 16 + l15;
          C[(size_t)grow * N + gcol] = f2bf(acc[m][n][j]);
        }
      }
    }
  }
}

// ---------------- SPMM D=256, bf16 gather -> f32 out (bias+leaky fused) ----------------

__global__ __launch_bounds__(256) void spmm_d256_kernel(const unsigned short* __restrict__ x, const int* __restrict__ rp,
                                                        const int* __restrict__ csrc, const float* __restrict__ cval,
                                                        const float* __restrict__ bias, float* __restrict__ out, int n) {
  int node = blockIdx.x * 4 + (threadIdx.x >> 6);
  int lane = threadIdx.x & 63;
  if (node >= n) return;
  int s = rp[node], e = rp[node + 1];
  float a0 = 0.f, a1 = 0.f, a2 = 0.f, a3 = 0.f;
  int p = s;
  for (; p + 8 <= e; p += 8) {
    int srcs[8];
    float vals[8];
    uint2 rv[8];
#pragma unroll
    for (int q = 0; q < 8; ++q) {
      srcs[q] = csrc[p + q];
      vals[q] = cval[p + q];
    }
#pragma unroll
    for (int q = 0; q < 8; ++q)
      rv[q] = *(const uint2*)((const char*)x + (size_t)srcs[q] * 512 + lane * 8);
#pragma unroll
    for (int q = 0; q < 8; ++q) {
      a0 = fmaf(vals[q], __uint_as_float(rv[q].x << 16), a0);
      a1 = fmaf(vals[q], __uint_as_float(rv[q].x & 0xffff0000u), a1);
      a2 = fmaf(vals[q], __uint_as_float(rv[q].y << 16), a2);
      a3 = fmaf(vals[q], __uint_as_float(rv[q].y & 0xffff0000u), a3);
    }
  }
  for (; p < e; ++p) {
    int s0 = csrc[p];
    float v0 = cval[p];
    uint2 r = *(const uint2*)((const char*)x + (size_t)s0 * 512 + lane * 8);
    a0 = fmaf(v0, __uint_as_float(r.x << 16), a0);
    a1 = fmaf(v0, __uint_as_float(r.x & 0xffff0000u), a1);
    a2 = fmaf(v0, __uint_as_float(r.y << 16), a2);
    a3 = fmaf(v0, __uint_as_float(r.y & 0xffff0000u), a3);
  }
  float4 b = *(const float4*)&bias[lane * 4];
  float4 o;
  o.x = leaky(a0 + b.x);
  o.y = leaky(a1 + b.y);
  o.z = leaky(a2 + b.z);
  o.w = leaky(a3 + b.w);
  *(float4*)&out[(size_t)node * 256 + lane * 4] = o;
}

// ---------------- SPMM small-D (40), bf16 gather (row stride ldx) -> f32 d_out ----------------

__global__ __launch_bounds__(256) void spmm_small_kernel(const unsigned short* __restrict__ x, const int* __restrict__ rp,
                                                         const int* __restrict__ csrc, const float* __restrict__ cval,
                                                         const float* __restrict__ bias, float* __restrict__ out,
                                                         int n, int D, int ldx) {
  int node = blockIdx.x * 4 + (threadIdx.x >> 6);
  int lane = threadIdx.x & 63;
  if (node >= n) return;
  int l = lane < D ? lane : 0;
  int s = rp[node], e = rp[node + 1];
  float acc = 0.f;
  int p = s;
  for (; p + 4 <= e; p += 4) {
    int s0 = csrc[p], s1 = csrc[p + 1], s2 = csrc[p + 2], s3 = csrc[p + 3];
    float v0 = cval[p], v1 = cval[p + 1], v2 = cval[p + 2], v3 = cval[p + 3];
    acc = fmaf(v0, bf2f(x[(size_t)s0 * ldx + l]), acc);
    acc = fmaf(v1, bf2f(x[(size_t)s1 * ldx + l]), acc);
    acc = fmaf(v2, bf2f(x[(size_t)s2 * ldx + l]), acc);
    acc = fmaf(v3, bf2f(x[(size_t)s3 * ldx + l]), acc);
  }
  for (; p < e; ++p) acc = fmaf(cval[p], bf2f(x[(size_t)csrc[p] * ldx + l]), acc);
  if (lane < D) {
    out[(size_t)node * D + lane] = leaky(acc + bias[lane]);
  }
}

// ---------------- launch ----------------

extern "C" void kernel_launch(void* const* d_in, const int* in_sizes, int n_in,
                              void* d_out, int out_size, void* d_ws, size_t ws_size,
                              hipStream_t stream) {
  const float* features = (const float*)d_in[0];
  const int* esrc = (const int*)d_in[1];
  const int* edst = (const int*)d_in[2];
  const float* evals = (const float*)d_in[3];
  const float* W1 = (const float*)d_in[4];
  const float* b1 = (const float*)d_in[5];
  const float* Wh = (const float*)d_in[6];
  const float* bh = (const float*)d_in[7];
  const float* W2 = (const float*)d_in[8];
  const float* b2 = (const float*)d_in[9];

  const int E = in_sizes[1];
  const int hid = in_sizes[5];          // 256
  const int ncls = in_sizes[9];         // 40
  const int nfeat = in_sizes[4] / hid;  // 512
  const int Nn = in_sizes[0] / nfeat;   // 100000
  const int nclsPad = 64;

  char* ws = (char*)d_ws;
  size_t off = 0;
  auto alloc = [&](size_t bytes) {
    char* p = ws + off;
    off += (bytes + 255) & ~(size_t)255;
    return p;
  };
  unsigned short* hA = (unsigned short*)alloc((size_t)Nn * hid * 2);  // bf16 GEMM outs (gathered)
  float* hB = (float*)alloc((size_t)Nn * hid * 4);                    // f32 spmm outs (GEMM ins)
  unsigned short* g3 = (unsigned short*)alloc((size_t)Nn * nclsPad * 2);
  unsigned short* Wt1 = (unsigned short*)alloc((size_t)hid * nfeat * 2);
  unsigned short* Wt2 = (unsigned short*)alloc((size_t)hid * hid * 2);
  unsigned short* Wt3 = (unsigned short*)alloc((size_t)nclsPad * hid * 2);
  int* rp = (int*)alloc((size_t)(Nn + 1) * 4);
  int* cursor = (int*)alloc((size_t)Nn * 4);
  int nb = (Nn + 2047) / 2048;
  int* bsum = (int*)alloc((size_t)nb * 4);
  int* csrc = (int*)alloc((size_t)E * 4);
  float* cval = (float*)alloc((size_t)E * 4);
  (void)ws_size;

  dim3 blk(256);

  // CSR build
  zero_int_kernel<<<(Nn + 255) / 256, blk, 0, stream>>>(cursor, Nn);
  hist_kernel<<<(E + 255) / 256, blk, 0, stream>>>(edst, cursor, E);
  scan1_kernel<<<nb, blk, 0, stream>>>(cursor, rp, bsum, Nn);
  scan2_kernel<<<1, 64, 0, stream>>>(bsum, nb, rp, Nn);
  scan3_kernel<<<(Nn + 255) / 256, blk, 0, stream>>>(rp, bsum, cursor, Nn);
  scatter_kernel<<<(E + 255) / 256, blk, 0, stream>>>(esrc, edst, evals, cursor, csrc, cval, E);

  // weights -> transposed bf16
  cvt_w_kernel<<<(hid * nfeat + 255) / 256, blk, 0, stream>>>(W1, Wt1, nfeat, hid, hid);
  cvt_w_kernel<<<(hid * hid + 255) / 256, blk, 0, stream>>>(Wh, Wt2, hid, hid, hid);
  cvt_w_kernel<<<(nclsPad * hid + 255) / 256, blk, 0, stream>>>(W2, Wt3, hid, ncls, nclsPad);

  int gm = (Nn + 127) / 128;

  // layer 1: GEMM [N,512]x[512,256] -> bf16 hA; spmm -> f32 hB
  gemm_mfma_kernel<<<dim3(gm, hid / 64), blk, 0, stream>>>(features, Wt1, hA, Nn, hid, nfeat);
  spmm_d256_kernel<<<(Nn + 3) / 4, blk, 0, stream>>>(hA, rp, csrc, cval, b1, hB, Nn);

  // layer 2
  gemm_mfma_kernel<<<dim3(gm, hid / 64), blk, 0, stream>>>(hB, Wt2, hA, Nn, hid, hid);
  spmm_d256_kernel<<<(Nn + 3) / 4, blk, 0, stream>>>(hA, rp, csrc, cval, bh, hB, Nn);

  // layer 3: GEMM [N,256]x[256,64pad] -> bf16 g3; spmm -> f32 d_out
  gemm_mfma_kernel<<<dim3(gm, nclsPad / 64), blk, 0, stream>>>(hB, Wt3, g3, Nn, nclsPad, hid);
  spmm_small_kernel<<<(Nn + 3) / 4, blk, 0, stream>>>(g3, rp, csrc, cval, b2, (float*)d_out, Nn, ncls, nclsPad);
}

// Round 9
// 1261.160 us; speedup vs baseline: 1.7355x; 1.0929x over previous
//
#include <hip/hip_runtime.h>

#define NEG_SLOPE 0.01f

typedef __attribute__((ext_vector_type(8))) short bf16x8;
typedef __attribute__((ext_vector_type(4))) float f32x4;

static __device__ __forceinline__ unsigned short f2bf(float f) {
  unsigned int u = __float_as_uint(f);
  return (unsigned short)((u + 0x7fffu + ((u >> 16) & 1u)) >> 16);  // RNE
}
static __device__ __forceinline__ float bf2f(unsigned short s) {
  return __uint_as_float(((unsigned int)s) << 16);
}
static __device__ __forceinline__ float leaky(float r) { return r > 0.f ? r : r * NEG_SLOPE; }

// ---------------- CSR build (verified) ----------------

__global__ __launch_bounds__(256) void zero_int_kernel(int* __restrict__ p, int n) {
  int i = blockIdx.x * 256 + threadIdx.x;
  if (i < n) p[i] = 0;
}

__global__ __launch_bounds__(256) void hist_kernel(const int* __restrict__ dst, int* __restrict__ cnt, int E) {
  int i = blockIdx.x * 256 + threadIdx.x;
  if (i < E) atomicAdd(&cnt[dst[i]], 1);
}

__global__ __launch_bounds__(256) void scan1_kernel(const int* __restrict__ cnt, int* __restrict__ rp,
                                                    int* __restrict__ bsum, int n) {
  __shared__ int sh[256];
  int t = threadIdx.x;
  int base = blockIdx.x * 2048 + t * 8;
  int v[8];
  int tot = 0;
#pragma unroll
  for (int j = 0; j < 8; ++j) {
    int i = base + j;
    int c = (i < n) ? cnt[i] : 0;
    v[j] = tot;
    tot += c;
  }
  sh[t] = tot;
  __syncthreads();
  for (int off = 1; off < 256; off <<= 1) {
    int x = sh[t];
    int y = (t >= off) ? sh[t - off] : 0;
    __syncthreads();
    sh[t] = x + y;
    __syncthreads();
  }
  int pre = sh[t] - tot;
#pragma unroll
  for (int j = 0; j < 8; ++j) {
    int i = base + j;
    if (i < n) rp[i] = pre + v[j];
  }
  if (t == 255) bsum[blockIdx.x] = sh[255];
}

__global__ void scan2_kernel(int* __restrict__ bsum, int nb, int* __restrict__ rp, int n) {
  if (threadIdx.x == 0 && blockIdx.x == 0) {
    int run = 0;
    for (int i = 0; i < nb; ++i) {
      int t = bsum[i];
      bsum[i] = run;
      run += t;
    }
    rp[n] = run;
  }
}

__global__ __launch_bounds__(256) void scan3_kernel(int* __restrict__ rp, const int* __restrict__ bsum,
                                                    int* __restrict__ cursor, int n) {
  int i = blockIdx.x * 256 + threadIdx.x;
  if (i < n) {
    int v = rp[i] + bsum[i >> 11];
    rp[i] = v;
    cursor[i] = v;
  }
}

__global__ __launch_bounds__(256) void scatter_kernel(const int* __restrict__ src, const int* __restrict__ dst,
                                                      const float* __restrict__ vals, int* __restrict__ cursor,
                                                      int* __restrict__ csrc, float* __restrict__ cval, int E) {
  int i = blockIdx.x * 256 + threadIdx.x;
  if (i < E) {
    int d = dst[i];
    int pos = atomicAdd(&cursor[d], 1);
    csrc[pos] = src[i];
    cval[pos] = vals[i];
  }
}

// ---------------- weight transpose + cvt ----------------

__global__ __launch_bounds__(256) void cvt_w_kernel(const float* __restrict__ W, unsigned short* __restrict__ Wt,
                                                    int K, int Nreal, int Npad) {
  int i = blockIdx.x * 256 + threadIdx.x;
  if (i >= Npad * K) return;
  int n = i / K, k = i - n * K;
  float v = (n < Nreal) ? W[(size_t)k * Nreal + n] : 0.f;
  Wt[i] = f2bf(v);
}

// ---------------- bf16 MFMA GEMM, full-width BN (A read exactly once) ----------------
// C[bf16, M x BN] = A[M x K] @ Wt^T, Wt is [BN][K] bf16 (pad rows zeroed).
// Tile 128 x BN, BK=64. Waves: 2 x WN grid, per-wave 64x64 output (4x4 16x16x32 frags).
// BN == full N of the layer -> grid.y == 1, A staged/read once per row-block.
// Fragment layout per learn_hip m89/m91/m92.

template <int BN, int WN, bool A_F32>
__global__ __launch_bounds__(128 * WN) void gemm_bf16_kernel(const void* __restrict__ Ap,
                                                             const unsigned short* __restrict__ Wt,
                                                             unsigned short* __restrict__ C, int M, int K) {
  constexpr int THREADS = 128 * WN;
  __shared__ __align__(16) short As[128 * 72];  // [row][k], +8 pad
  __shared__ __align__(16) short Bs[BN * 72];   // [n][k]
  const int t = threadIdx.x;
  const int lane = t & 63;
  const int w = t >> 6;
  const int wr = w / WN;  // 0..1
  const int wc = w % WN;  // 0..WN-1
  const int row0 = blockIdx.x * 128;
  const int l15 = lane & 15;
  const int l16 = lane >> 4;  // 0..3

  f32x4 acc[4][4];
#pragma unroll
  for (int m = 0; m < 4; ++m)
#pragma unroll
    for (int n = 0; n < 4; ++n) acc[m][n] = (f32x4){0.f, 0.f, 0.f, 0.f};

  for (int k0 = 0; k0 < K; k0 += 64) {
    __syncthreads();  // previous tile's LDS reads done
    if constexpr (A_F32) {
      const float* A = (const float*)Ap;
#pragma unroll
      for (int it = 0; it < 2048 / THREADS; ++it) {
        int idx = it * THREADS + t;
        int row = idx >> 4, c4 = idx & 15;
        int grow = row0 + row;
        float4 v = make_float4(0.f, 0.f, 0.f, 0.f);
        if (grow < M) v = *(const float4*)&A[(size_t)grow * K + k0 + c4 * 4];
        unsigned int lo = (unsigned int)f2bf(v.x) | ((unsigned int)f2bf(v.y) << 16);
        unsigned int hi = (unsigned int)f2bf(v.z) | ((unsigned int)f2bf(v.w) << 16);
        *(uint2*)&As[row * 72 + c4 * 4] = make_uint2(lo, hi);
      }
    } else {
      const unsigned short* A = (const unsigned short*)Ap;
#pragma unroll
      for (int it = 0; it < 1024 / THREADS; ++it) {
        int idx = it * THREADS + t;
        int row = idx >> 3, c8 = idx & 7;
        int grow = row0 + row;
        uint4 v = make_uint4(0u, 0u, 0u, 0u);
        if (grow < M) v = *(const uint4*)&A[(size_t)grow * K + c8 * 8 + k0];
        *(uint4*)&As[row * 72 + c8 * 8] = v;
      }
    }
    // B tile BN x 64 bf16
#pragma unroll
    for (int it = 0; it < BN * 8 / THREADS; ++it) {
      int idx = it * THREADS + t;
      int n = idx >> 3, c8 = idx & 7;
      uint4 v = *(const uint4*)&Wt[(size_t)n * K + k0 + c8 * 8];
      *(uint4*)&Bs[n * 72 + c8 * 8] = v;
    }
    __syncthreads();
#pragma unroll
    for (int kk = 0; kk < 64; kk += 32) {
      bf16x8 a[4], b[4];
#pragma unroll
      for (int m = 0; m < 4; ++m)
        a[m] = *(const bf16x8*)&As[(wr * 64 + m * 16 + l15) * 72 + kk + l16 * 8];
#pragma unroll
      for (int n = 0; n < 4; ++n)
        b[n] = *(const bf16x8*)&Bs[(wc * 64 + n * 16 + l15) * 72 + kk + l16 * 8];
#pragma unroll
      for (int m = 0; m < 4; ++m)
#pragma unroll
        for (int n = 0; n < 4; ++n)
          acc[m][n] = __builtin_amdgcn_mfma_f32_16x16x32_bf16(a[m], b[n], acc[m][n], 0, 0, 0);
    }
  }
  // epilogue: C row-major, ld = BN
#pragma unroll
  for (int m = 0; m < 4; ++m) {
#pragma unroll
    for (int j = 0; j < 4; ++j) {
      int grow = row0 + wr * 64 + m * 16 + l16 * 4 + j;
      if (grow < M) {
#pragma unroll
        for (int n = 0; n < 4; ++n) {
          int gcol = wc * 64 + n * 16 + l15;
          C[(size_t)grow * BN + gcol] = f2bf(acc[m][n][j]);
        }
      }
    }
  }
}

// ---------------- SPMM D=256, bf16 gather -> bf16 out (bias+leaky fused) ----------------

__global__ __launch_bounds__(256) void spmm_d256_kernel(const unsigned short* __restrict__ x, const int* __restrict__ rp,
                                                        const int* __restrict__ csrc, const float* __restrict__ cval,
                                                        const float* __restrict__ bias, unsigned short* __restrict__ out,
                                                        int n) {
  int node = blockIdx.x * 4 + (threadIdx.x >> 6);
  int lane = threadIdx.x & 63;
  if (node >= n) return;
  int s = rp[node], e = rp[node + 1];
  float a0 = 0.f, a1 = 0.f, a2 = 0.f, a3 = 0.f;
  int p = s;
  for (; p + 8 <= e; p += 8) {
    int srcs[8];
    float vals[8];
    uint2 rv[8];
#pragma unroll
    for (int q = 0; q < 8; ++q) {
      srcs[q] = csrc[p + q];
      vals[q] = cval[p + q];
    }
#pragma unroll
    for (int q = 0; q < 8; ++q)
      rv[q] = *(const uint2*)((const char*)x + (size_t)srcs[q] * 512 + lane * 8);
#pragma unroll
    for (int q = 0; q < 8; ++q) {
      a0 = fmaf(vals[q], __uint_as_float(rv[q].x << 16), a0);
      a1 = fmaf(vals[q], __uint_as_float(rv[q].x & 0xffff0000u), a1);
      a2 = fmaf(vals[q], __uint_as_float(rv[q].y << 16), a2);
      a3 = fmaf(vals[q], __uint_as_float(rv[q].y & 0xffff0000u), a3);
    }
  }
  for (; p < e; ++p) {
    int s0 = csrc[p];
    float v0 = cval[p];
    uint2 r = *(const uint2*)((const char*)x + (size_t)s0 * 512 + lane * 8);
    a0 = fmaf(v0, __uint_as_float(r.x << 16), a0);
    a1 = fmaf(v0, __uint_as_float(r.x & 0xffff0000u), a1);
    a2 = fmaf(v0, __uint_as_float(r.y << 16), a2);
    a3 = fmaf(v0, __uint_as_float(r.y & 0xffff0000u), a3);
  }
  float4 b = *(const float4*)&bias[lane * 4];
  unsigned int o01 = (unsigned int)f2bf(leaky(a0 + b.x)) | ((unsigned int)f2bf(leaky(a1 + b.y)) << 16);
  unsigned int o23 = (unsigned int)f2bf(leaky(a2 + b.z)) | ((unsigned int)f2bf(leaky(a3 + b.w)) << 16);
  *(uint2*)&out[(size_t)node * 256 + lane * 4] = make_uint2(o01, o23);
}

// ---------------- SPMM small-D (40), bf16 gather (row stride ldx) -> f32 d_out ----------------

__global__ __launch_bounds__(256) void spmm_small_kernel(const unsigned short* __restrict__ x, const int* __restrict__ rp,
                                                         const int* __restrict__ csrc, const float* __restrict__ cval,
                                                         const float* __restrict__ bias, float* __restrict__ out,
                                                         int n, int D, int ldx) {
  int node = blockIdx.x * 4 + (threadIdx.x >> 6);
  int lane = threadIdx.x & 63;
  if (node >= n) return;
  int l = lane < D ? lane : 0;
  int s = rp[node], e = rp[node + 1];
  float acc = 0.f;
  int p = s;
  for (; p + 4 <= e; p += 4) {
    int s0 = csrc[p], s1 = csrc[p + 1], s2 = csrc[p + 2], s3 = csrc[p + 3];
    float v0 = cval[p], v1 = cval[p + 1], v2 = cval[p + 2], v3 = cval[p + 3];
    acc = fmaf(v0, bf2f(x[(size_t)s0 * ldx + l]), acc);
    acc = fmaf(v1, bf2f(x[(size_t)s1 * ldx + l]), acc);
    acc = fmaf(v2, bf2f(x[(size_t)s2 * ldx + l]), acc);
    acc = fmaf(v3, bf2f(x[(size_t)s3 * ldx + l]), acc);
  }
  for (; p < e; ++p) acc = fmaf(cval[p], bf2f(x[(size_t)csrc[p] * ldx + l]), acc);
  if (lane < D) {
    out[(size_t)node * D + lane] = leaky(acc + bias[lane]);
  }
}

// ---------------- launch ----------------

extern "C" void kernel_launch(void* const* d_in, const int* in_sizes, int n_in,
                              void* d_out, int out_size, void* d_ws, size_t ws_size,
                              hipStream_t stream) {
  const float* features = (const float*)d_in[0];
  const int* esrc = (const int*)d_in[1];
  const int* edst = (const int*)d_in[2];
  const float* evals = (const float*)d_in[3];
  const float* W1 = (const float*)d_in[4];
  const float* b1 = (const float*)d_in[5];
  const float* Wh = (const float*)d_in[6];
  const float* bh = (const float*)d_in[7];
  const float* W2 = (const float*)d_in[8];
  const float* b2 = (const float*)d_in[9];

  const int E = in_sizes[1];
  const int hid = in_sizes[5];          // 256
  const int ncls = in_sizes[9];         // 40
  const int nfeat = in_sizes[4] / hid;  // 512
  const int Nn = in_sizes[0] / nfeat;   // 100000
  const int nclsPad = 64;

  char* ws = (char*)d_ws;
  size_t off = 0;
  auto alloc = [&](size_t bytes) {
    char* p = ws + off;
    off += (bytes + 255) & ~(size_t)255;
    return p;
  };
  unsigned short* hA = (unsigned short*)alloc((size_t)Nn * hid * 2);  // GEMM outs (gathered by spmm)
  unsigned short* hB = (unsigned short*)alloc((size_t)Nn * hid * 2);  // spmm outs (GEMM A-ins), bf16
  unsigned short* g3 = (unsigned short*)alloc((size_t)Nn * nclsPad * 2);
  unsigned short* Wt1 = (unsigned short*)alloc((size_t)hid * nfeat * 2);
  unsigned short* Wt2 = (unsigned short*)alloc((size_t)hid * hid * 2);
  unsigned short* Wt3 = (unsigned short*)alloc((size_t)nclsPad * hid * 2);
  int* rp = (int*)alloc((size_t)(Nn + 1) * 4);
  int* cursor = (int*)alloc((size_t)Nn * 4);
  int nb = (Nn + 2047) / 2048;
  int* bsum = (int*)alloc((size_t)nb * 4);
  int* csrc = (int*)alloc((size_t)E * 4);
  float* cval = (float*)alloc((size_t)E * 4);
  (void)ws_size;

  dim3 blk(256);

  // CSR build
  zero_int_kernel<<<(Nn + 255) / 256, blk, 0, stream>>>(cursor, Nn);
  hist_kernel<<<(E + 255) / 256, blk, 0, stream>>>(edst, cursor, E);
  scan1_kernel<<<nb, blk, 0, stream>>>(cursor, rp, bsum, Nn);
  scan2_kernel<<<1, 64, 0, stream>>>(bsum, nb, rp, Nn);
  scan3_kernel<<<(Nn + 255) / 256, blk, 0, stream>>>(rp, bsum, cursor, Nn);
  scatter_kernel<<<(E + 255) / 256, blk, 0, stream>>>(esrc, edst, evals, cursor, csrc, cval, E);

  // weights -> transposed bf16 (pad rows zeroed)
  cvt_w_kernel<<<(hid * nfeat + 255) / 256, blk, 0, stream>>>(W1, Wt1, nfeat, hid, hid);
  cvt_w_kernel<<<(hid * hid + 255) / 256, blk, 0, stream>>>(Wh, Wt2, hid, hid, hid);
  cvt_w_kernel<<<(nclsPad * hid + 255) / 256, blk, 0, stream>>>(W2, Wt3, hid, ncls, nclsPad);

  int gm = (Nn + 127) / 128;

  // layer 1: GEMM [N,512]x[512,256] (A f32, read once) -> bf16 hA; spmm -> bf16 hB
  gemm_bf16_kernel<256, 4, true><<<dim3(gm, 1), dim3(512), 0, stream>>>(features, Wt1, hA, Nn, nfeat);
  spmm_d256_kernel<<<(Nn + 3) / 4, blk, 0, stream>>>(hA, rp, csrc, cval, b1, hB, Nn);

  // layer 2: GEMM [N,256]x[256,256] (A bf16) -> hA; spmm -> hB
  gemm_bf16_kernel<256, 4, false><<<dim3(gm, 1), dim3(512), 0, stream>>>(hB, Wt2, hA, Nn, hid);
  spmm_d256_kernel<<<(Nn + 3) / 4, blk, 0, stream>>>(hA, rp, csrc, cval, bh, hB, Nn);

  // layer 3: GEMM [N,256]x[256,64pad] (A bf16) -> g3; spmm -> f32 d_out
  gemm_bf16_kernel<64, 1, false><<<dim3(gm, 1), dim3(128), 0, stream>>>(hB, Wt3, g3, Nn, hid);
  spmm_small_kernel<<<(Nn + 3) / 4, blk, 0, stream>>>(g3, rp, csrc, cval, b2, (float*)d_out, Nn, ncls, nclsPad);
}